// Round 1
// baseline (1242.853 us; speedup 1.0000x reference)
//
#include <hip/hip_runtime.h>
#include <math.h>

// Problem constants (fixed by the reference)
#define BN 256     // batch N
#define TT 1000    // timesteps
#define NO 10      // obs dim
#define NS 10      // state dim
#define HID 64     // GRU hidden
#define DIN 20     // NO + NS
#define G3 192     // 3*HID

// broadcast lane `l`'s value of v to all lanes as a scalar (SGPR)
__device__ __forceinline__ float bcast(float v, int l) {
    return __int_as_float(__builtin_amdgcn_readlane(__float_as_int(v), l));
}

// ---------------- Phase 1: GRU recurrence, one wave per sample -------------
// Writes raw (pre-bias, pre-softplus) mu/var projections: ws[(n*TT+t)*DIN + c]
//   c in [0,10): h_t @ W_mu column c ; c in [10,20): h_t @ W_var column c-10
__global__ __launch_bounds__(64, 1)
void gru_phase1(const float* __restrict__ Yi, const float* __restrict__ Xh,
                const float* __restrict__ Wi, const float* __restrict__ Wh,
                const float* __restrict__ bi, const float* __restrict__ bh,
                const float* __restrict__ Wmu, const float* __restrict__ Wvar,
                float* __restrict__ mv_out) {
    const int n = blockIdx.x;
    const int lane = threadIdx.x;   // 0..63, = hidden unit index

    // Per-lane weight columns (registers)
    float whr[HID], whz[HID], whn[HID], wmv[HID];
    float wir[DIN], wiz[DIN], win[DIN];
#pragma unroll
    for (int k = 0; k < HID; ++k) {
        whr[k] = Wh[k * G3 + lane];
        whz[k] = Wh[k * G3 + 64 + lane];
        whn[k] = Wh[k * G3 + 128 + lane];
        float wm = (lane < NS) ? Wmu[k * NS + lane] : 0.0f;
        float wv = (lane >= NS && lane < 2 * NS) ? Wvar[k * NS + (lane - NS)] : 0.0f;
        wmv[k] = wm + wv;   // packed: lanes 0..9 -> W_mu, lanes 10..19 -> W_var
    }
#pragma unroll
    for (int k = 0; k < DIN; ++k) {
        wir[k] = Wi[k * G3 + lane];
        wiz[k] = Wi[k * G3 + 64 + lane];
        win[k] = Wi[k * G3 + 128 + lane];
    }
    const float b_r  = bi[lane] + bh[lane];
    const float b_z  = bi[64 + lane] + bh[64 + lane];
    const float bx_n = bi[128 + lane];
    const float bh_n = bh[128 + lane];

    const float* ybase = Yi + (size_t)n * TT * NO;
    const float* xbase = Xh + (size_t)n * TT * NS;
    float* obase = mv_out + (size_t)n * TT * DIN;

    float h = 0.0f;
    // x-input prefetch (lanes 0..19 hold concat(y, xhat) element `lane`)
    float xv_cur = 0.0f, xv_nxt = 0.0f;
    if (lane < DIN) {
        xv_cur = (lane < NO) ? ybase[lane] : xbase[lane - NO];
        xv_nxt = (lane < NO) ? ybase[NO + lane] : xbase[NS + (lane - NO)];
    }

#pragma unroll 1
    for (int t = 0; t < TT; ++t) {
        float ar = b_r, az = b_z, anx = bx_n, anh = bh_n, amv = 0.0f;
        // input projection (xin = concat(y, xhat), lane k<20 holds xin[k])
#pragma unroll
        for (int k = 0; k < DIN; ++k) {
            float s = bcast(xv_cur, k);
            ar += s * wir[k];
            az += s * wiz[k];
            anx += s * win[k];
        }
        // hidden projection from h_{t-1}; amv belongs to output index t-1
#pragma unroll
        for (int k = 0; k < HID; ++k) {
            float s = bcast(h, k);
            ar += s * whr[k];
            az += s * whz[k];
            anh += s * whn[k];
            amv += s * wmv[k];
        }
        if (t > 0 && lane < DIN) obase[(size_t)(t - 1) * DIN + lane] = amv;

        float r = 1.0f / (1.0f + __expf(-ar));
        float z = 1.0f / (1.0f + __expf(-az));
        float pre = anx + r * anh;
        pre = fminf(fmaxf(pre, -15.0f), 15.0f);      // tanh saturation guard
        float e2 = __expf(2.0f * pre);
        float nn = (e2 - 1.0f) / (e2 + 1.0f);
        h = nn + z * (h - nn);                        // (1-z)*n + z*h

        // rotate input prefetch (2 ahead)
        xv_cur = xv_nxt;
        if (lane < DIN && (t + 2) < TT) {
            int t2 = t + 2;
            xv_nxt = (lane < NO) ? ybase[t2 * NO + lane] : xbase[t2 * NS + (lane - NO)];
        }
    }
    // final output row t = TT-1 from h_{TT-1}
    {
        float amv = 0.0f;
#pragma unroll
        for (int k = 0; k < HID; ++k) amv += bcast(h, k) * wmv[k];
        if (lane < DIN) obase[(size_t)(TT - 1) * DIN + lane] = amv;
    }
}

// ---------------- d_out init: the constant term ----------------------------
__global__ void init_out(float* out) {
    // -0.5*log(2*pi): the -0.5*NO*T*log(2pi) term divided by (T*NO)
    out[0] = -0.918938533204672742f;
}

// ---------------- Phase 2: per-(n,t) Gaussian log-lik ----------------------
__global__ __launch_bounds__(256)
void lik_phase2(const float* __restrict__ Yi, const float* __restrict__ Cw,
                const float* __restrict__ Hm, const float* __restrict__ mu_w,
                const float* __restrict__ b_mu, const float* __restrict__ b_var,
                const float* __restrict__ mv_in, float* __restrict__ out) {
    __shared__ float sH[NO * NS];
    __shared__ float smw[NO], sbm[NS], sbv[NS];
    __shared__ float ssum[4];
    const int tid = threadIdx.x;
    if (tid < NO * NS) sH[tid] = Hm[tid];
    if (tid < NO) smw[tid] = mu_w[tid];
    if (tid < NS) { sbm[tid] = b_mu[tid]; sbv[tid] = b_var[tid]; }
    __syncthreads();

    const int gid = blockIdx.x * 256 + tid;   // 0 .. BN*TT-1
    float contrib = 0.0f;
    if (gid < BN * TT) {
        const int n = gid / TT;
        const float* mv = mv_in + (size_t)gid * DIN;
        float mu[NS], va[NS];
#pragma unroll
        for (int i = 0; i < NS; ++i) {
            mu[i] = mv[i] + sbm[i];
            float x = mv[NS + i] + sbv[i];
            // stable softplus
            va[i] = (x > 0.0f) ? (x + log1pf(__expf(-x))) : log1pf(__expf(x));
        }
        const float* y = Yi + (size_t)gid * NO;
        float e[NO];
#pragma unroll
        for (int i = 0; i < NO; ++i) {
            float m = smw[i];
#pragma unroll
            for (int j = 0; j < NS; ++j) m += sH[i * NS + j] * mu[j];
            e[i] = y[i] - m;
        }
        // M = H diag(va) H^T + Cw (lower triangle only)
        float M[NO][NO];
        const float* cw = Cw + (size_t)n * NO * NO;
#pragma unroll
        for (int i = 0; i < NO; ++i)
#pragma unroll
            for (int j = 0; j <= i; ++j) M[i][j] = cw[i * NO + j];
#pragma unroll
        for (int l = 0; l < NS; ++l) {
            float vl = va[l];
            float hv[NO];
#pragma unroll
            for (int i = 0; i < NO; ++i) hv[i] = sH[i * NS + l];
#pragma unroll
            for (int i = 0; i < NO; ++i) {
                float hvi = hv[i] * vl;
#pragma unroll
                for (int j = 0; j <= i; ++j) M[i][j] += hvi * hv[j];
            }
        }
        // in-place Cholesky (lower), logdet = sum log(d_j)
        float logdet = 0.0f;
#pragma unroll
        for (int j = 0; j < NO; ++j) {
            float d = M[j][j];
#pragma unroll
            for (int k = 0; k < j; ++k) d -= M[j][k] * M[j][k];
            logdet += __logf(d);
            float s = sqrtf(d);
            M[j][j] = s;
            float inv = 1.0f / s;
#pragma unroll
            for (int i = j + 1; i < NO; ++i) {
                float v = M[i][j];
#pragma unroll
                for (int k = 0; k < j; ++k) v -= M[i][k] * M[j][k];
                M[i][j] = v * inv;
            }
        }
        // quad = || L^-1 e ||^2 (forward solve)
        float w[NO];
        float quad = 0.0f;
#pragma unroll
        for (int i = 0; i < NO; ++i) {
            float v = e[i];
#pragma unroll
            for (int k = 0; k < i; ++k) v -= M[i][k] * w[k];
            w[i] = v / M[i][i];
            quad += w[i] * w[i];
        }
        const float SCALE = 0.5f / ((float)BN * (float)TT * (float)NO);
        contrib = -(logdet + quad) * SCALE;
    }

    // block reduction: wave shuffle, then LDS across 4 waves, one atomic
#pragma unroll
    for (int off = 32; off > 0; off >>= 1) contrib += __shfl_down(contrib, off);
    if ((tid & 63) == 0) ssum[tid >> 6] = contrib;
    __syncthreads();
    if (tid == 0) {
        float s = ssum[0] + ssum[1] + ssum[2] + ssum[3];
        atomicAdd(out, s);
    }
}

// ---------------- launch ---------------------------------------------------
extern "C" void kernel_launch(void* const* d_in, const int* in_sizes, int n_in,
                              void* d_out, int out_size, void* d_ws, size_t ws_size,
                              hipStream_t stream) {
    const float* Yi    = (const float*)d_in[0];
    const float* Xh    = (const float*)d_in[1];
    const float* Cw    = (const float*)d_in[2];
    const float* Hm    = (const float*)d_in[3];
    const float* mu_w  = (const float*)d_in[4];
    const float* Wi    = (const float*)d_in[5];
    const float* Wh    = (const float*)d_in[6];
    const float* bi    = (const float*)d_in[7];
    const float* bh    = (const float*)d_in[8];
    const float* W_mu  = (const float*)d_in[9];
    const float* b_mu  = (const float*)d_in[10];
    const float* W_var = (const float*)d_in[11];
    const float* b_var = (const float*)d_in[12];
    float* out = (float*)d_out;
    float* mv  = (float*)d_ws;   // [BN*TT*DIN] floats = 20.48 MB

    init_out<<<1, 1, 0, stream>>>(out);
    gru_phase1<<<dim3(BN), dim3(64), 0, stream>>>(Yi, Xh, Wi, Wh, bi, bh,
                                                  W_mu, W_var, mv);
    lik_phase2<<<dim3((BN * TT + 255) / 256), dim3(256), 0, stream>>>(
        Yi, Cw, Hm, mu_w, b_mu, b_var, mv, out);
}

// Round 2
// 1008.429 us; speedup vs baseline: 1.2325x; 1.2325x over previous
//
#include <hip/hip_runtime.h>
#include <math.h>

// Problem constants (fixed by the reference)
#define BN 256     // batch N
#define TT 1000    // timesteps
#define NO 10      // obs dim
#define NS 10      // state dim
#define HID 64     // GRU hidden
#define DIN 20     // NO + NS
#define G3 192     // 3*HID
#define WV 4       // waves per sample (k-split)
#define KW 16      // HID / WV
#define DW 5       // DIN / WV

// broadcast lane `l`'s value of v to all lanes (l may be a wave-uniform value)
__device__ __forceinline__ float bcast(float v, int l) {
    return __int_as_float(__builtin_amdgcn_readlane(__float_as_int(v), l));
}

// ---------------- Phase 1: GRU recurrence, 4 waves per sample --------------
// Wave w handles k in [16w,16w+16) of the h-projection and input dims
// [5w,5w+5). Partial sums exchanged through double-buffered LDS; every wave
// redundantly reduces + applies the nonlinearity so h stays in registers.
// Output: raw (pre-bias, pre-softplus) mu/var projections of h_t:
//   ws[(n*TT+t)*DIN + c], c<10: h@W_mu col c ; c>=10: h@W_var col c-10
__global__ __launch_bounds__(256, 1)
void gru_phase1(const float* __restrict__ Yi, const float* __restrict__ Xh,
                const float* __restrict__ Wi, const float* __restrict__ Wh,
                const float* __restrict__ bi, const float* __restrict__ bh,
                const float* __restrict__ Wmu, const float* __restrict__ Wvar,
                float* __restrict__ mv_out) {
    const int n = blockIdx.x;
    const int tid = threadIdx.x;
    const int lane = tid & 63;      // hidden unit index
    const int w = tid >> 6;         // wave id 0..3
    const int kb = w * KW;          // k-range base (hidden)
    const int db = w * DW;          // k-range base (input)

    // [buffer][wave][acc][lane]; accs: 0=r 1=z 2=nx 3=nh 4=mv. 10 KB.
    __shared__ float part[2][WV][5][HID];

    // Per-lane weight slices (registers; ~110 VGPRs total -> no spill)
    float whr[KW], whz[KW], whn[KW], wmv[KW];
    float wir[DW], wiz[DW], win[DW];
#pragma unroll
    for (int k = 0; k < KW; ++k) {
        const int kk = kb + k;
        whr[k] = Wh[kk * G3 + lane];
        whz[k] = Wh[kk * G3 + 64 + lane];
        whn[k] = Wh[kk * G3 + 128 + lane];
        float wm = (lane < NS) ? Wmu[kk * NS + lane] : 0.0f;
        float wv = (lane >= NS && lane < 2 * NS) ? Wvar[kk * NS + (lane - NS)] : 0.0f;
        wmv[k] = wm + wv;   // packed: lanes 0..9 -> W_mu, lanes 10..19 -> W_var
    }
#pragma unroll
    for (int k = 0; k < DW; ++k) {
        const int kk = db + k;
        wir[k] = Wi[kk * G3 + lane];
        wiz[k] = Wi[kk * G3 + 64 + lane];
        win[k] = Wi[kk * G3 + 128 + lane];
    }
    const float b_r  = bi[lane] + bh[lane];
    const float b_z  = bi[64 + lane] + bh[64 + lane];
    const float bx_n = bi[128 + lane];
    const float bh_n = bh[128 + lane];

    const float* ybase = Yi + (size_t)n * TT * NO;
    const float* xbase = Xh + (size_t)n * TT * NS;
    float* obase = mv_out + (size_t)n * TT * DIN;

    float h = 0.0f;
    // x-input prefetch (lanes 0..19 hold concat(y, xhat); loaded by all waves)
    float xv_cur = 0.0f, xv_nxt = 0.0f;
    if (lane < DIN) {
        xv_cur = (lane < NO) ? ybase[lane] : xbase[lane - NO];
        xv_nxt = (lane < NO) ? ybase[NO + lane] : xbase[NS + (lane - NO)];
    }

#pragma unroll 1
    for (int t = 0; t < TT; ++t) {
        float p0 = 0.0f, p1 = 0.0f, p2 = 0.0f, p3 = 0.0f, p4 = 0.0f;
        // input-projection partial (this wave's 5 input dims)
#pragma unroll
        for (int k = 0; k < DW; ++k) {
            float s = bcast(xv_cur, db + k);
            p0 += s * wir[k]; p1 += s * wiz[k]; p2 += s * win[k];
        }
        // hidden-projection partial (this wave's 16 k's); p4 is for output t-1
#pragma unroll
        for (int k = 0; k < KW; ++k) {
            float s = bcast(h, kb + k);
            p0 += s * whr[k]; p1 += s * whz[k]; p3 += s * whn[k]; p4 += s * wmv[k];
        }
        const int buf = t & 1;
        part[buf][w][0][lane] = p0;
        part[buf][w][1][lane] = p1;
        part[buf][w][2][lane] = p2;
        part[buf][w][3][lane] = p3;
        part[buf][w][4][lane] = p4;
        __syncthreads();
        // redundant all-wave reduce (conflict-free: addr = const + lane*4)
        float ar = b_r, az = b_z, ax = bx_n, ah = bh_n, amv = 0.0f;
#pragma unroll
        for (int ww = 0; ww < WV; ++ww) {
            ar  += part[buf][ww][0][lane];
            az  += part[buf][ww][1][lane];
            ax  += part[buf][ww][2][lane];
            ah  += part[buf][ww][3][lane];
            amv += part[buf][ww][4][lane];
        }
        if (w == 0 && t > 0 && lane < DIN)
            obase[(size_t)(t - 1) * DIN + lane] = amv;

        float r = __fdividef(1.0f, 1.0f + __expf(-ar));
        float z = __fdividef(1.0f, 1.0f + __expf(-az));
        float pre = ax + r * ah;
        pre = fminf(fmaxf(pre, -15.0f), 15.0f);      // tanh saturation guard
        float e2 = __expf(2.0f * pre);
        float nn = __fdividef(e2 - 1.0f, e2 + 1.0f);
        h = nn + z * (h - nn);                        // (1-z)*n + z*h

        // rotate input prefetch (2 ahead)
        xv_cur = xv_nxt;
        if (lane < DIN && (t + 2) < TT) {
            const int t2 = t + 2;
            xv_nxt = (lane < NO) ? ybase[t2 * NO + lane] : xbase[t2 * NS + (lane - NO)];
        }
    }
    // final output row t = TT-1 from h_{TT-1}
    {
        float p4 = 0.0f;
#pragma unroll
        for (int k = 0; k < KW; ++k) p4 += bcast(h, kb + k) * wmv[k];
        part[0][w][4][lane] = p4;   // buf0: last read at t=998, fenced by t=999 barrier
        __syncthreads();
        if (w == 0 && lane < DIN) {
            float amv = 0.0f;
#pragma unroll
            for (int ww = 0; ww < WV; ++ww) amv += part[0][ww][4][lane];
            obase[(size_t)(TT - 1) * DIN + lane] = amv;
        }
    }
}

// ---------------- d_out init: the constant term ----------------------------
__global__ void init_out(float* out) {
    // -0.5*NO*T*log(2pi) / (T*NO) = -0.5*log(2pi)
    out[0] = -0.918938533204672742f;
}

// ---------------- Phase 2: per-(n,t) Gaussian log-lik ----------------------
__global__ __launch_bounds__(256)
void lik_phase2(const float* __restrict__ Yi, const float* __restrict__ Cw,
                const float* __restrict__ Hm, const float* __restrict__ mu_w,
                const float* __restrict__ b_mu, const float* __restrict__ b_var,
                const float* __restrict__ mv_in, float* __restrict__ out) {
    __shared__ float sH[NO * NS];
    __shared__ float smw[NO], sbm[NS], sbv[NS];
    __shared__ float ssum[4];
    const int tid = threadIdx.x;
    if (tid < NO * NS) sH[tid] = Hm[tid];
    if (tid < NO) smw[tid] = mu_w[tid];
    if (tid < NS) { sbm[tid] = b_mu[tid]; sbv[tid] = b_var[tid]; }
    __syncthreads();

    const int gid = blockIdx.x * 256 + tid;   // 0 .. BN*TT-1
    float contrib = 0.0f;
    if (gid < BN * TT) {
        const int n = gid / TT;
        const float* mv = mv_in + (size_t)gid * DIN;
        float mu[NS], va[NS];
#pragma unroll
        for (int i = 0; i < NS; ++i) {
            mu[i] = mv[i] + sbm[i];
            float x = mv[NS + i] + sbv[i];
            va[i] = (x > 0.0f) ? (x + log1pf(__expf(-x))) : log1pf(__expf(x));
        }
        const float* y = Yi + (size_t)gid * NO;
        float e[NO];
#pragma unroll
        for (int i = 0; i < NO; ++i) {
            float m = smw[i];
#pragma unroll
            for (int j = 0; j < NS; ++j) m += sH[i * NS + j] * mu[j];
            e[i] = y[i] - m;
        }
        // M = H diag(va) H^T + Cw (lower triangle only)
        float M[NO][NO];
        const float* cw = Cw + (size_t)n * NO * NO;
#pragma unroll
        for (int i = 0; i < NO; ++i)
#pragma unroll
            for (int j = 0; j <= i; ++j) M[i][j] = cw[i * NO + j];
#pragma unroll
        for (int l = 0; l < NS; ++l) {
            float vl = va[l];
            float hv[NO];
#pragma unroll
            for (int i = 0; i < NO; ++i) hv[i] = sH[i * NS + l];
#pragma unroll
            for (int i = 0; i < NO; ++i) {
                float hvi = hv[i] * vl;
#pragma unroll
                for (int j = 0; j <= i; ++j) M[i][j] += hvi * hv[j];
            }
        }
        // in-place Cholesky (lower), logdet = sum log d_j
        float logdet = 0.0f;
#pragma unroll
        for (int j = 0; j < NO; ++j) {
            float d = M[j][j];
#pragma unroll
            for (int k = 0; k < j; ++k) d -= M[j][k] * M[j][k];
            logdet += __logf(d);
            float s = sqrtf(d);
            M[j][j] = s;
            float inv = 1.0f / s;
#pragma unroll
            for (int i = j + 1; i < NO; ++i) {
                float v = M[i][j];
#pragma unroll
                for (int k = 0; k < j; ++k) v -= M[i][k] * M[j][k];
                M[i][j] = v * inv;
            }
        }
        // quad = || L^-1 e ||^2 (forward solve)
        float wv[NO];
        float quad = 0.0f;
#pragma unroll
        for (int i = 0; i < NO; ++i) {
            float v = e[i];
#pragma unroll
            for (int k = 0; k < i; ++k) v -= M[i][k] * wv[k];
            wv[i] = v / M[i][i];
            quad += wv[i] * wv[i];
        }
        const float SCALE = 0.5f / ((float)BN * (float)TT * (float)NO);
        contrib = -(logdet + quad) * SCALE;
    }

    // block reduction: wave shuffle, LDS across 4 waves, one atomic
#pragma unroll
    for (int off = 32; off > 0; off >>= 1) contrib += __shfl_down(contrib, off);
    if ((tid & 63) == 0) ssum[tid >> 6] = contrib;
    __syncthreads();
    if (tid == 0) {
        float s = ssum[0] + ssum[1] + ssum[2] + ssum[3];
        atomicAdd(out, s);
    }
}

// ---------------- launch ---------------------------------------------------
extern "C" void kernel_launch(void* const* d_in, const int* in_sizes, int n_in,
                              void* d_out, int out_size, void* d_ws, size_t ws_size,
                              hipStream_t stream) {
    const float* Yi    = (const float*)d_in[0];
    const float* Xh    = (const float*)d_in[1];
    const float* Cw    = (const float*)d_in[2];
    const float* Hm    = (const float*)d_in[3];
    const float* mu_w  = (const float*)d_in[4];
    const float* Wi    = (const float*)d_in[5];
    const float* Wh    = (const float*)d_in[6];
    const float* bi    = (const float*)d_in[7];
    const float* bh    = (const float*)d_in[8];
    const float* W_mu  = (const float*)d_in[9];
    const float* b_mu  = (const float*)d_in[10];
    const float* W_var = (const float*)d_in[11];
    const float* b_var = (const float*)d_in[12];
    float* out = (float*)d_out;
    float* mv  = (float*)d_ws;   // [BN*TT*DIN] floats = 20.48 MB

    init_out<<<1, 1, 0, stream>>>(out);
    gru_phase1<<<dim3(BN), dim3(256), 0, stream>>>(Yi, Xh, Wi, Wh, bi, bh,
                                                   W_mu, W_var, mv);
    lik_phase2<<<dim3((BN * TT + 255) / 256), dim3(256), 0, stream>>>(
        Yi, Cw, Hm, mu_w, b_mu, b_var, mv, out);
}

// Round 3
// 632.405 us; speedup vs baseline: 1.9653x; 1.5946x over previous
//
#include <hip/hip_runtime.h>
#include <math.h>

// Problem constants (fixed by the reference)
#define BN 256     // batch N
#define TT 1000    // timesteps
#define NO 10      // obs dim
#define NS 10      // state dim
#define HID 64     // GRU hidden
#define DIN 20     // NO + NS
#define G3 192     // 3*HID
#define WV 4       // waves per sample (k-split)
#define KW 16      // HID / WV
#define GS 8       // steps per group (1000 = 125 * 8)
#define NG 125     // groups

// broadcast lane `l`'s value of v to all lanes (l wave-uniform)
__device__ __forceinline__ float bcast(float v, int l) {
    return __int_as_float(__builtin_amdgcn_readlane(__float_as_int(v), l));
}
__device__ __forceinline__ float rcpf(float x) { return __builtin_amdgcn_rcpf(x); }

// ---------------- Phase 1: GRU recurrence, 4 waves per sample --------------
// Wave w: k in [16w,16w+16) of the h-projection; input dims [5w,5w+5).
// All global I/O batched per 8-step group through LDS (the per-step
// __syncthreads emits s_waitcnt vmcnt(0): any global op inside the step
// window costs a full memory round-trip per step — R2's 2244 cyc/step bug).
__global__ __launch_bounds__(256, 1)
void gru_phase1(const float* __restrict__ Yi, const float* __restrict__ Xh,
                const float* __restrict__ Wi, const float* __restrict__ Wh,
                const float* __restrict__ bi, const float* __restrict__ bh,
                const float* __restrict__ Wmu, const float* __restrict__ Wvar,
                float* __restrict__ mv_out) {
    const int n = blockIdx.x;
    const int tid = threadIdx.x;
    const int lane = tid & 63;      // hidden unit index
    const int w = tid >> 6;         // wave id 0..3
    const int kb = w * KW;          // k-range base (hidden)

    // partial sums: [buf][acc][wave][lane]; accs: 0=r 1=z 2=nx 3=nh 4=mv (10 KB)
    __shared__ float part[2][5][WV][HID];
    // input staging: per group 160 floats = [y(8 steps x 10) | x(8 steps x 10)]
    __shared__ float inbuf[2][GS * DIN];
    // output staging: per group 160 floats = [step][20]
    __shared__ float obuf[2][GS * DIN];

    // Per-lane weight slices (registers)
    float whr[KW], whz[KW], whn[KW], wmv[KW];
    float wir[5], wiz[5], win[5];
#pragma unroll
    for (int k = 0; k < KW; ++k) {
        const int kk = kb + k;
        whr[k] = Wh[kk * G3 + lane];
        whz[k] = Wh[kk * G3 + 64 + lane];
        whn[k] = Wh[kk * G3 + 128 + lane];
        float wm = (lane < NS) ? Wmu[kk * NS + lane] : 0.0f;
        float wv = (lane >= NS && lane < 2 * NS) ? Wvar[kk * NS + (lane - NS)] : 0.0f;
        wmv[k] = wm + wv;   // packed: lanes 0..9 -> W_mu, lanes 10..19 -> W_var
    }
#pragma unroll
    for (int k = 0; k < 5; ++k) {
        const int kk = 5 * w + k;   // this wave's input dims
        wir[k] = Wi[kk * G3 + lane];
        wiz[k] = Wi[kk * G3 + 64 + lane];
        win[k] = Wi[kk * G3 + 128 + lane];
    }
    const float b_r  = bi[lane] + bh[lane];
    const float b_z  = bi[64 + lane] + bh[64 + lane];
    const float bx_n = bi[128 + lane];
    const float bh_n = bh[128 + lane];

    const float* ybase = Yi + (size_t)n * TT * NO;
    const float* xbase = Xh + (size_t)n * TT * NS;
    float* obase = mv_out + (size_t)n * TT * DIN;

    // LDS offset of this wave's 5 input dims within a step row
    const int ibase = ((w >= 2) ? 80 : 0) + (w & 1) * 5;

    // prologue: stage group 0
    if (tid < 160)
        inbuf[0][tid] = (tid < 80) ? ybase[tid] : xbase[tid - 80];
    __syncthreads();

    float h = 0.0f;

#pragma unroll 1
    for (int g = 0; g < NG; ++g) {
        // issue next group's coalesced load (drains at first barrier; ~once/group)
        float ld = 0.0f;
        const bool do_ld = (tid < 160) && (g + 1 < NG);
        if (do_ld)
            ld = (tid < 80) ? ybase[(size_t)(g + 1) * 80 + tid]
                            : xbase[(size_t)(g + 1) * 80 + tid - 80];
        const float* ib = inbuf[g & 1];

#pragma unroll
        for (int s = 0; s < GS; ++s) {
            // ---- partials (pre-barrier phase) ----
            const float* ip = ib + ibase + s * 10;
            const float x0 = ip[0], x1 = ip[1], x2 = ip[2], x3 = ip[3], x4 = ip[4];
            float pr = x0 * wir[0], pz = x0 * wiz[0], px = x0 * win[0];
            pr += x1 * wir[1]; pz += x1 * wiz[1]; px += x1 * win[1];
            pr += x2 * wir[2]; pz += x2 * wiz[2]; px += x2 * win[2];
            pr += x3 * wir[3]; pz += x3 * wiz[3]; px += x3 * win[3];
            pr += x4 * wir[4]; pz += x4 * wiz[4]; px += x4 * win[4];
            float pra = 0, prb = 0, pza = 0, pzb = 0;
            float pna = 0, pnb = 0, pma = 0, pmb = 0;
#pragma unroll
            for (int k = 0; k < 8; ++k) {
                float sv = bcast(h, kb + k);
                pra += sv * whr[k]; pza += sv * whz[k];
                pna += sv * whn[k]; pma += sv * wmv[k];
            }
#pragma unroll
            for (int k = 8; k < KW; ++k) {
                float sv = bcast(h, kb + k);
                prb += sv * whr[k]; pzb += sv * whz[k];
                pnb += sv * whn[k]; pmb += sv * wmv[k];
            }
            const int bufp = s & 1;      // t = 8g+s, parity = s&1
            part[bufp][0][w][lane] = pr + pra + prb;
            part[bufp][1][w][lane] = pz + pza + pzb;
            part[bufp][2][w][lane] = px;
            part[bufp][3][w][lane] = pna + pnb;
            part[bufp][4][w][lane] = pma + pmb;
            // stage next group's inputs just before the group's last barrier
            if (s == GS - 1 && do_ld) inbuf[(g + 1) & 1][tid] = ld;
            __syncthreads();

            // ---- reduce + nonlinearity (post-barrier phase) ----
            float ar = b_r, az = b_z, ax = bx_n, ah = bh_n;
#pragma unroll
            for (int ww = 0; ww < WV; ++ww) {
                ar += part[bufp][0][ww][lane];
                az += part[bufp][1][ww][lane];
                ax += part[bufp][2][ww][lane];
                ah += part[bufp][3][ww][lane];
            }
            if (w == 0) {   // amv for output t-1 (wave 0 only)
                float amv = part[bufp][4][0][lane] + part[bufp][4][1][lane]
                          + part[bufp][4][2][lane] + part[bufp][4][3][lane];
                if (lane < DIN && !(g == 0 && s == 0)) {
                    const int tm1 = 8 * g + s - 1;
                    obuf[(tm1 >> 3) & 1][(tm1 & 7) * DIN + lane] = amv;
                }
            }
            // flush previous output group (post-barrier; slot 7 was stashed
            // after the s==0 barrier, ordered by the s==1 barrier)
            if (s == 1 && g >= 1 && tid < 160)
                obase[(size_t)(g - 1) * 160 + tid] = obuf[(g - 1) & 1][tid];

            float r = rcpf(1.0f + __expf(-ar));
            float z = rcpf(1.0f + __expf(-az));
            float pre = ax + r * ah;
            pre = fminf(fmaxf(pre, -15.0f), 15.0f);
            float e2 = __expf(2.0f * pre);
            float nn = 1.0f - 2.0f * rcpf(e2 + 1.0f);   // tanh(pre)
            h = nn + z * (h - nn);
        }
    }

    // epilogue: output 999 from h_999, then flush output group 124
    {
        float pma = 0, pmb = 0;
#pragma unroll
        for (int k = 0; k < 8; ++k) pma += bcast(h, kb + k) * wmv[k];
#pragma unroll
        for (int k = 8; k < KW; ++k) pmb += bcast(h, kb + k) * wmv[k];
        part[0][4][w][lane] = pma + pmb;   // t=1000 parity 0; safe vs t=998 reads
        __syncthreads();
        if (w == 0 && lane < DIN) {
            float amv = part[0][4][0][lane] + part[0][4][1][lane]
                      + part[0][4][2][lane] + part[0][4][3][lane];
            obuf[0][7 * DIN + lane] = amv;  // output 999: group 124, slot 7, buf 0
        }
        __syncthreads();
        if (tid < 160)
            obase[(size_t)(NG - 1) * 160 + tid] = obuf[0][tid];
    }
}

// ---------------- d_out init: the constant term ----------------------------
__global__ void init_out(float* out) {
    // -0.5*NO*T*log(2pi) / (T*NO) = -0.5*log(2pi)
    out[0] = -0.918938533204672742f;
}

// ---------------- Phase 2: per-(n,t) Gaussian log-lik ----------------------
__global__ __launch_bounds__(256)
void lik_phase2(const float* __restrict__ Yi, const float* __restrict__ Cw,
                const float* __restrict__ Hm, const float* __restrict__ mu_w,
                const float* __restrict__ b_mu, const float* __restrict__ b_var,
                const float* __restrict__ mv_in, float* __restrict__ out) {
    __shared__ float sH[NO * NS];
    __shared__ float smw[NO], sbm[NS], sbv[NS];
    __shared__ float ssum[4];
    const int tid = threadIdx.x;
    if (tid < NO * NS) sH[tid] = Hm[tid];
    if (tid < NO) smw[tid] = mu_w[tid];
    if (tid < NS) { sbm[tid] = b_mu[tid]; sbv[tid] = b_var[tid]; }
    __syncthreads();

    const int gid = blockIdx.x * 256 + tid;   // 0 .. BN*TT-1
    float contrib = 0.0f;
    if (gid < BN * TT) {
        const int n = gid / TT;
        const float* mv = mv_in + (size_t)gid * DIN;
        float mu[NS], va[NS];
#pragma unroll
        for (int i = 0; i < NS; ++i) {
            mu[i] = mv[i] + sbm[i];
            float x = mv[NS + i] + sbv[i];
            va[i] = (x > 0.0f) ? (x + log1pf(__expf(-x))) : log1pf(__expf(x));
        }
        const float* y = Yi + (size_t)gid * NO;
        float e[NO];
#pragma unroll
        for (int i = 0; i < NO; ++i) {
            float m = smw[i];
#pragma unroll
            for (int j = 0; j < NS; ++j) m += sH[i * NS + j] * mu[j];
            e[i] = y[i] - m;
        }
        // M = H diag(va) H^T + Cw (lower triangle only)
        float M[NO][NO];
        const float* cw = Cw + (size_t)n * NO * NO;
#pragma unroll
        for (int i = 0; i < NO; ++i)
#pragma unroll
            for (int j = 0; j <= i; ++j) M[i][j] = cw[i * NO + j];
#pragma unroll
        for (int l = 0; l < NS; ++l) {
            float vl = va[l];
            float hv[NO];
#pragma unroll
            for (int i = 0; i < NO; ++i) hv[i] = sH[i * NS + l];
#pragma unroll
            for (int i = 0; i < NO; ++i) {
                float hvi = hv[i] * vl;
#pragma unroll
                for (int j = 0; j <= i; ++j) M[i][j] += hvi * hv[j];
            }
        }
        // in-place Cholesky (lower), logdet = sum log d_j
        float logdet = 0.0f;
#pragma unroll
        for (int j = 0; j < NO; ++j) {
            float d = M[j][j];
#pragma unroll
            for (int k = 0; k < j; ++k) d -= M[j][k] * M[j][k];
            logdet += __logf(d);
            float s = sqrtf(d);
            M[j][j] = s;
            float inv = 1.0f / s;
#pragma unroll
            for (int i = j + 1; i < NO; ++i) {
                float v = M[i][j];
#pragma unroll
                for (int k = 0; k < j; ++k) v -= M[i][k] * M[j][k];
                M[i][j] = v * inv;
            }
        }
        // quad = || L^-1 e ||^2 (forward solve)
        float wv[NO];
        float quad = 0.0f;
#pragma unroll
        for (int i = 0; i < NO; ++i) {
            float v = e[i];
#pragma unroll
            for (int k = 0; k < i; ++k) v -= M[i][k] * wv[k];
            wv[i] = v / M[i][i];
            quad += wv[i] * wv[i];
        }
        const float SCALE = 0.5f / ((float)BN * (float)TT * (float)NO);
        contrib = -(logdet + quad) * SCALE;
    }

    // block reduction: wave shuffle, LDS across 4 waves, one atomic
#pragma unroll
    for (int off = 32; off > 0; off >>= 1) contrib += __shfl_down(contrib, off);
    if ((tid & 63) == 0) ssum[tid >> 6] = contrib;
    __syncthreads();
    if (tid == 0) {
        float s = ssum[0] + ssum[1] + ssum[2] + ssum[3];
        atomicAdd(out, s);
    }
}

// ---------------- launch ---------------------------------------------------
extern "C" void kernel_launch(void* const* d_in, const int* in_sizes, int n_in,
                              void* d_out, int out_size, void* d_ws, size_t ws_size,
                              hipStream_t stream) {
    const float* Yi    = (const float*)d_in[0];
    const float* Xh    = (const float*)d_in[1];
    const float* Cw    = (const float*)d_in[2];
    const float* Hm    = (const float*)d_in[3];
    const float* mu_w  = (const float*)d_in[4];
    const float* Wi    = (const float*)d_in[5];
    const float* Wh    = (const float*)d_in[6];
    const float* bi    = (const float*)d_in[7];
    const float* bh    = (const float*)d_in[8];
    const float* W_mu  = (const float*)d_in[9];
    const float* b_mu  = (const float*)d_in[10];
    const float* W_var = (const float*)d_in[11];
    const float* b_var = (const float*)d_in[12];
    float* out = (float*)d_out;
    float* mv  = (float*)d_ws;   // [BN*TT*DIN] floats = 20.48 MB

    init_out<<<1, 1, 0, stream>>>(out);
    gru_phase1<<<dim3(BN), dim3(256), 0, stream>>>(Yi, Xh, Wi, Wh, bi, bh,
                                                   W_mu, W_var, mv);
    lik_phase2<<<dim3((BN * TT + 255) / 256), dim3(256), 0, stream>>>(
        Yi, Cw, Hm, mu_w, b_mu, b_var, mv, out);
}